// Round 12
// baseline (152.739 us; speedup 1.0000x reference)
//
#include <hip/hip_runtime.h>
#include <cstdint>
#include <cstddef>

#define N_  16
#define C_  64
#define H_  224
#define W_  224
#define HW_ (H_ * W_)      // 50176
#define NHW_ (N_ * HW_)    // 802816

typedef unsigned long long u64;
typedef float f32x4 __attribute__((ext_vector_type(4)));

// ---------------------------------------------------------------------------
// ws layout (bytes):
//   [0,      16384) double2 part[64*16]   per-(c,n) partial {sum, sumsq}
//   [17152,  21760) u64   wbits[64*9]     weight sign bits packed over C
//   [32768, +6.4MB) u64   abits[16*50176] activation sign bits packed over C
// ---------------------------------------------------------------------------

__global__ void k_stats(const float* __restrict__ x, double2* __restrict__ part) {
    int b = blockIdx.x;          // (n,c)
    int c = b & 63;
    int n = b >> 6;
    const float4* px = (const float4*)(x + (size_t)(n * 64 + c) * HW_);
    double s = 0.0, ss = 0.0;
    for (int i = threadIdx.x; i < HW_ / 4; i += 256) {
        float4 v = px[i];
        s  += (double)v.x + (double)v.y + (double)v.z + (double)v.w;
        ss += (double)v.x * v.x + (double)v.y * v.y
            + (double)v.z * v.z + (double)v.w * v.w;
    }
    __shared__ double sh_s[256];
    __shared__ double sh_q[256];
    sh_s[threadIdx.x] = s;
    sh_q[threadIdx.x] = ss;
    __syncthreads();
    for (int off = 128; off > 0; off >>= 1) {
        if (threadIdx.x < (unsigned)off) {
            sh_s[threadIdx.x] += sh_s[threadIdx.x + off];
            sh_q[threadIdx.x] += sh_q[threadIdx.x + off];
        }
        __syncthreads();
    }
    if (threadIdx.x == 0) part[c * 16 + n] = make_double2(sh_s[0], sh_q[0]);
}

// one thread = 4 consecutive spatial positions, all 64 channels.
// scale/bias computed inline from part. Block (0,0) also packs wbits.
__global__ void k_binpack(const float* __restrict__ x,
                          const double2* __restrict__ part,
                          const float* __restrict__ gamma,
                          const float* __restrict__ beta,
                          const float* __restrict__ weight,
                          u64* __restrict__ wbits,
                          u64* __restrict__ abits) {
    __shared__ float s_scale[64];
    __shared__ float s_bias[64];
    int t = threadIdx.x;
    if (t < 64) {
        double s = 0.0, ss = 0.0;
#pragma unroll
        for (int nn = 0; nn < 16; ++nn) {
            double2 p = part[t * 16 + nn];
            s += p.x; ss += p.y;
        }
        double mean = s / (double)NHW_;
        double var  = ss / (double)NHW_ - mean * mean;
        double inv  = 1.0 / sqrt(var + 1e-5);
        double g    = (double)gamma[t];
        s_scale[t] = (float)(g * inv);
        s_bias[t]  = (float)((double)beta[t] - mean * g * inv);
    }
    __syncthreads();
    int p4 = blockIdx.x * 256 + t;             // quad within image, 0..12543
    int n  = blockIdx.y;
    const float* px = x + (size_t)n * 64 * HW_ + (size_t)p4 * 4;

    unsigned lo0 = 0, lo1 = 0, lo2 = 0, lo3 = 0;
    unsigned hi0 = 0, hi1 = 0, hi2 = 0, hi3 = 0;
#pragma unroll 8
    for (int c = 0; c < 32; ++c) {
        float4 v = *(const float4*)(px + (size_t)c * HW_);
        float sc = s_scale[c], bi = s_bias[c];
        lo0 |= (fmaf(v.x, sc, bi) < 0.0f ? 1u : 0u) << c;
        lo1 |= (fmaf(v.y, sc, bi) < 0.0f ? 1u : 0u) << c;
        lo2 |= (fmaf(v.z, sc, bi) < 0.0f ? 1u : 0u) << c;
        lo3 |= (fmaf(v.w, sc, bi) < 0.0f ? 1u : 0u) << c;
    }
#pragma unroll 8
    for (int c = 32; c < 64; ++c) {
        float4 v = *(const float4*)(px + (size_t)c * HW_);
        float sc = s_scale[c], bi = s_bias[c];
        hi0 |= (fmaf(v.x, sc, bi) < 0.0f ? 1u : 0u) << (c - 32);
        hi1 |= (fmaf(v.y, sc, bi) < 0.0f ? 1u : 0u) << (c - 32);
        hi2 |= (fmaf(v.z, sc, bi) < 0.0f ? 1u : 0u) << (c - 32);
        hi3 |= (fmaf(v.w, sc, bi) < 0.0f ? 1u : 0u) << (c - 32);
    }
    u64* dst = abits + (size_t)n * HW_ + (size_t)p4 * 4;
    ulonglong2 w01, w23;
    w01.x = (u64)lo0 | ((u64)hi0 << 32);
    w01.y = (u64)lo1 | ((u64)hi1 << 32);
    w23.x = (u64)lo2 | ((u64)hi2 << 32);
    w23.y = (u64)lo3 | ((u64)hi3 << 32);
    *(ulonglong2*)(dst)     = w01;
    *(ulonglong2*)(dst + 2) = w23;

    // block (0,0): pack weight sign words (576 u64), hidden under binpack
    if (blockIdx.x == 0 && blockIdx.y == 0) {
        for (int i = t; i < 576; i += 256) {
            int o = i / 9, k = i - o * 9;
            u64 b = 0;
#pragma unroll
            for (int j = 0; j < 64; ++j) {
                float wv = weight[(size_t)(o * 64 + j) * 9 + k];
                if (wv < 0.0f) b |= (1ull << j);
            }
            wbits[i] = b;
        }
    }
}

// ---------------- conv ----------------
// LDS-staged: block = (2-row strip, n). 4 A-rows staged to LDS, then hoisted
// ONCE into registers (A-windows are channel-invariant); per-channel loop is
// pure-VALU popcount with x/W/alpha software-pipelined one iteration ahead.

__device__ __forceinline__ void ldwin(const u64* __restrict__ rb, u64 A[6]) {
    // rb = lds_row + 5*lane ; offsets {0,1,2,3,5,6} = words w0-1 .. w0+4
    A[0] = rb[0]; A[1] = rb[1]; A[2] = rb[2];
    A[3] = rb[3]; A[4] = rb[5]; A[5] = rb[6];
}

__device__ __forceinline__ void racc6(const u64 A[6], const u64* __restrict__ W3,
                                      int& s0, int& s1, int& s2, int& s3) {
    s0 += (int)(__popcll(A[0] ^ W3[0]) + __popcll(A[1] ^ W3[1]) + __popcll(A[2] ^ W3[2]));
    s1 += (int)(__popcll(A[1] ^ W3[0]) + __popcll(A[2] ^ W3[1]) + __popcll(A[3] ^ W3[2]));
    s2 += (int)(__popcll(A[2] ^ W3[0]) + __popcll(A[3] ^ W3[1]) + __popcll(A[4] ^ W3[2]));
    s3 += (int)(__popcll(A[3] ^ W3[0]) + __popcll(A[4] ^ W3[1]) + __popcll(A[5] ^ W3[2]));
}

#define RS_ 284   // u64 slots per LDS row (226 words + pads, 16B-aligned stride)

__global__ __launch_bounds__(256)
void k_conv(const float* __restrict__ x,
            const u64* __restrict__ abits,
            const u64* __restrict__ wbits,
            const float* __restrict__ alpha,
            float* __restrict__ out) {
    __shared__ u64 lds[4 * RS_ + 12];
    const int lane = threadIdx.x & 63;
    const int wid  = threadIdx.x >> 6;
    const int n    = 15 - (int)blockIdx.y;      // reversed: L3-warmest first
    const int h0   = (int)blockIdx.x * 2;       // strip of 2 output rows

    // ---- stage A-rows h0-1 .. h0+2 (zero-filled if out of range) ----
    {
        const int r = h0 - 1 + wid;
        u64* dst = lds + wid * RS_;
        if (lane < 56) {
            u64 a0 = 0, a1 = 0, a2 = 0, a3 = 0;
            if (r >= 0 && r < 224) {
                const u64* p = abits + (size_t)n * HW_ + (size_t)r * 224 + lane * 4;
                ulonglong2 lo = *(const ulonglong2*)p;
                ulonglong2 hi = *(const ulonglong2*)(p + 2);
                a0 = lo.x; a1 = lo.y; a2 = hi.x; a3 = hi.y;
            }
            int i = 5 * lane;            // slot 4L+1 -> idx 5L+1 etc.
            dst[i + 1] = a0; dst[i + 2] = a1; dst[i + 3] = a2; dst[i + 5] = a3;
        } else if (lane == 56) {
            dst[0] = 0;                  // slot 0 sentinel (word -1)
            dst[281] = 0;                // slot 225 sentinel (word 224)
        }
    }
    __syncthreads();

    const int os = __builtin_amdgcn_readfirstlane(wid);  // provably uniform
    const bool act = (lane < 56);
    const int xlane = act ? lane : 0;   // CLAMP: keep inactive-lane loads in-bounds
    const bool v0 = (lane != 0), v5 = (lane != 55);
    const bool topv = (h0 > 0);     // row h0 has a real top neighbor
    const bool botv = (h0 < 222);   // row h0+1 has a real bottom neighbor

    // ---- hoist the 4 channel-invariant A-windows into registers (once) ----
    u64 A0[6], A1[6], A2[6], A3[6];
    ldwin(lds + 0 * RS_ + 5 * lane, A0);
    ldwin(lds + 1 * RS_ + 5 * lane, A1);
    ldwin(lds + 2 * RS_ + 5 * lane, A2);
    ldwin(lds + 3 * RS_ + 5 * lane, A3);

    // ---- software-pipelined channel loop: prefetch W / alpha / x one ahead ----
    u64 Wc[9];
    {
        const u64* wb = wbits + os * 9;
#pragma unroll
        for (int k = 0; k < 9; ++k) Wc[k] = wb[k];
    }
    float alc = alpha[os];
    size_t xoc = ((size_t)(n * 64 + os)) * HW_ + (size_t)h0 * 224 + xlane * 4;
    f32x4 xr0c = *(const f32x4*)(x + xoc);
    f32x4 xr1c = *(const f32x4*)(x + xoc + 224);

#pragma unroll 2
    for (int oi = 0; oi < 16; ++oi) {
        u64 Wn[9];
        float aln;
        f32x4 xr0n, xr1n;
        size_t xon = xoc;
        if (oi < 15) {
            const int on = ((oi + 1) << 2) | os;            // scalar
            xon = ((size_t)(n * 64 + on)) * HW_ + (size_t)h0 * 224 + xlane * 4;
            xr0n = *(const f32x4*)(x + xon);                // issue early
            xr1n = *(const f32x4*)(x + xon + 224);
            const u64* wb = wbits + on * 9;                 // s_load
#pragma unroll
            for (int k = 0; k < 9; ++k) Wn[k] = wb[k];
            aln = alpha[on];
        }

        int pc[9];
#pragma unroll
        for (int k = 0; k < 9; ++k) pc[k] = (int)__popcll(Wc[k]);
        int b0c[3], b3c[3], sc[3];
#pragma unroll
        for (int d = 0; d < 3; ++d) {
            b0c[d] = v0 ? 192 : 128 + 2 * pc[3*d+0];
            b3c[d] = v5 ? 192 : 128 + 2 * pc[3*d+2];
            sc[d]  = 2 * (pc[3*d] + pc[3*d+1] + pc[3*d+2]);  // zero-row comp
        }
        const int B0r0 = (topv ? b0c[0] : sc[0]) + b0c[1] + b0c[2];
        const int B3r0 = (topv ? b3c[0] : sc[0]) + b3c[1] + b3c[2];
        const int nbr0 = (topv ? 192    : sc[0]) + 384;
        const int B0r1 = b0c[0] + b0c[1] + (botv ? b0c[2] : sc[2]);
        const int B3r1 = b3c[0] + b3c[1] + (botv ? b3c[2] : sc[2]);
        const int nbr1 = 384 + (botv ? 192 : sc[2]);

        if (act) {
            // output row h0
            int s0 = 0, s1 = 0, s2 = 0, s3 = 0;
            racc6(A0, Wc + 0, s0, s1, s2, s3);
            racc6(A1, Wc + 3, s0, s1, s2, s3);
            racc6(A2, Wc + 6, s0, s1, s2, s3);
            f32x4 y0;
            y0.x = fmaf(alc, (float)(B0r0 - 2 * s0), xr0c.x);
            y0.y = fmaf(alc, (float)(nbr0 - 2 * s1), xr0c.y);
            y0.z = fmaf(alc, (float)(nbr0 - 2 * s2), xr0c.z);
            y0.w = fmaf(alc, (float)(B3r0 - 2 * s3), xr0c.w);
            __builtin_nontemporal_store(y0, (f32x4*)(out + xoc));
            // output row h0+1
            int t0 = 0, t1 = 0, t2 = 0, t3 = 0;
            racc6(A1, Wc + 0, t0, t1, t2, t3);
            racc6(A2, Wc + 3, t0, t1, t2, t3);
            racc6(A3, Wc + 6, t0, t1, t2, t3);
            f32x4 y1;
            y1.x = fmaf(alc, (float)(B0r1 - 2 * t0), xr1c.x);
            y1.y = fmaf(alc, (float)(nbr1 - 2 * t1), xr1c.y);
            y1.z = fmaf(alc, (float)(nbr1 - 2 * t2), xr1c.z);
            y1.w = fmaf(alc, (float)(B3r1 - 2 * t3), xr1c.w);
            __builtin_nontemporal_store(y1, (f32x4*)(out + xoc + 224));
        }

        // rotate pipeline (only when a new stage was fetched)
        if (oi < 15) {
#pragma unroll
            for (int k = 0; k < 9; ++k) Wc[k] = Wn[k];
            alc = aln; xr0c = xr0n; xr1c = xr1n; xoc = xon;
        }
    }
}

extern "C" void kernel_launch(void* const* d_in, const int* in_sizes, int n_in,
                              void* d_out, int out_size, void* d_ws, size_t ws_size,
                              hipStream_t stream) {
    const float* x      = (const float*)d_in[0];
    const float* gamma  = (const float*)d_in[1];
    const float* beta   = (const float*)d_in[2];
    const float* weight = (const float*)d_in[3];
    const float* alpha  = (const float*)d_in[4];
    float* out = (float*)d_out;

    char* ws = (char*)d_ws;
    double2* part  = (double2*)(ws + 0);
    u64*     wbits = (u64*)(ws + 17152);
    u64*     abits = (u64*)(ws + 32768);

    k_stats   <<<N_ * C_, 256, 0, stream>>>(x, part);
    k_binpack <<<dim3((HW_ / 4) / 256, N_), 256, 0, stream>>>(x, part, gamma, beta,
                                                              weight, wbits, abits);
    k_conv    <<<dim3(112, 16), 256, 0, stream>>>(x, abits, wbits, alpha, out);
}